// Round 12
// baseline (358.103 us; speedup 1.0000x reference)
//
#include <hip/hip_runtime.h>
#include <hip/hip_fp16.h>

#define T_LEN   262144
#define NV      20
#define NE      30
#define NH      40
#define CHUNK   256
#define WARM    64
#define SPC     (WARM + CHUNK)         // 320
#define NBLK    (T_LEN / CHUNK)        // 1024
#define SS      32                     // steps per super-step
#define NSS     (SPC / SS)             // 10
#define WUSS    (WARM / SS)            // 2
#define NTHR    128
#define NW4     1600                   // uint4 count: W_hh packs
#define NW4L    200                    // uint4 count: W_l packs

typedef _Float16 half2v __attribute__((ext_vector_type(2)));
typedef unsigned u32x2  __attribute__((ext_vector_type(2)));
typedef unsigned u32x4  __attribute__((ext_vector_type(4)));

__device__ __forceinline__ float sig_(float x) {
    x = fminf(fmaxf(x, -30.f), 30.f);
    return __fdividef(1.f, 1.f + __expf(-x));
}
__device__ __forceinline__ float tanh_(float x) {
    x = fminf(fmaxf(x, -15.f), 15.f);
    float e = __expf(2.f * x);
    return __fdividef(e - 1.f, e + 1.f);
}
__device__ __forceinline__ unsigned pkf_(float a, float b) {
    unsigned lo = (unsigned)__half_as_ushort(__float2half(a));
    unsigned hi = (unsigned)__half_as_ushort(__float2half(b));
    return lo | (hi << 16);
}
__device__ __forceinline__ float lo16f_(unsigned u) {
    return __half2float(__ushort_as_half((unsigned short)(u & 0xffffu)));
}
__device__ __forceinline__ float hi16f_(unsigned u) {
    return __half2float(__ushort_as_half((unsigned short)(u >> 16)));
}
__device__ __forceinline__ float dot2_(unsigned hp, unsigned wp, float c) {
#if __has_builtin(__builtin_amdgcn_fdot2)
    return __builtin_amdgcn_fdot2(__builtin_bit_cast(half2v, hp),
                                  __builtin_bit_cast(half2v, wp), c, false);
#else
    __half2 h = __builtin_bit_cast(__half2, hp);
    __half2 w = __builtin_bit_cast(__half2, wp);
    return fmaf(__half2float(h.x), __half2float(w.x),
           fmaf(__half2float(h.y), __half2float(w.y), c));
#endif
}
// Opaque 16B load: asm-produced values cannot be rematerialized.
__device__ __forceinline__ uint4 gload16_(const uint4* p) {
    uint4 r;
    asm volatile("global_load_dwordx4 %0, %1, off\n\ts_waitcnt vmcnt(0)"
                 : "=v"(r) : "v"(p) : "memory");
    return r;
}

#define D20(V) unsigned V##0,V##1,V##2,V##3,V##4,V##5,V##6,V##7,V##8,V##9, \
    V##10,V##11,V##12,V##13,V##14,V##15,V##16,V##17,V##18,V##19
#define A20(V, C0, C1, C2, C3, C4) do { \
    V##0 =C0.x; V##1 =C0.y; V##2 =C0.z; V##3 =C0.w; \
    V##4 =C1.x; V##5 =C1.y; V##6 =C1.z; V##7 =C1.w; \
    V##8 =C2.x; V##9 =C2.y; V##10=C2.z; V##11=C2.w; \
    V##12=C3.x; V##13=C3.y; V##14=C3.z; V##15=C3.w; \
    V##16=C4.x; V##17=C4.y; V##18=C4.z; V##19=C4.w; } while(0)

// One chunk Q handles h-pairs 4Q..4Q+3: i/f dots from registers, g/o dots
// from LDS (one ds_read_b128 each, imm-offset from an opaque base so the
// loop-invariant reads can't be LICM-hoisted back into registers).
#define ACHUNK(Q, A, B, C, D) do { \
    u32x4 vg = wgo[(0 * 5 + (Q)) * NH]; \
    u32x4 vo = wgo[(1 * 5 + (Q)) * NH]; \
    unsigned hp; \
    hp = (unsigned)__builtin_amdgcn_readlane(hpair, 8*(Q)+0); \
    ai = dot2_(hp, w##A,  ai); af = dot2_(hp, wf##A, af); \
    ag = dot2_(hp, vg[0], ag); ao = dot2_(hp, vo[0], ao); \
    hp = (unsigned)__builtin_amdgcn_readlane(hpair, 8*(Q)+2); \
    ai = dot2_(hp, w##B,  ai); af = dot2_(hp, wf##B, af); \
    ag = dot2_(hp, vg[1], ag); ao = dot2_(hp, vo[1], ao); \
    hp = (unsigned)__builtin_amdgcn_readlane(hpair, 8*(Q)+4); \
    ai = dot2_(hp, w##C,  ai); af = dot2_(hp, wf##C, af); \
    ag = dot2_(hp, vg[2], ag); ao = dot2_(hp, vo[2], ao); \
    hp = (unsigned)__builtin_amdgcn_readlane(hpair, 8*(Q)+6); \
    ai = dot2_(hp, w##D,  ai); af = dot2_(hp, wf##D, af); \
    ag = dot2_(hp, vg[3], ag); ao = dot2_(hp, vo[3], ao); \
} while(0)

// ---- prep kernel: pack weights as f16 pairs into d_ws ----
// wsW[((dir*4+g)*5+m4)*40+k] = uint4 of pairs m=4*m4+u of W_hh[g*40+k][.]
// wsW[1600 + (dir*5+m4)*20+v] = uint4 of pairs of W_l[v][.]
extern "C" __global__ void prep_kernel(const float* __restrict__ W_hh1,
                                       const float* __restrict__ W_hh2,
                                       const float* __restrict__ W_l1,
                                       const float* __restrict__ W_l2,
                                       uint4* __restrict__ ws)
{
    int tid = blockIdx.x * blockDim.x + threadIdx.x;
    for (int p = tid; p < NW4 + NW4L; p += blockDim.x * gridDim.x) {
        uint4 o;
        if (p < NW4) {
            int k = p % NH, r = p / NH;
            int m4 = r % 5;  r /= 5;
            int g  = r % 4;
            int dd = r / 4;
            const float* W = dd ? W_hh2 : W_hh1;
            const float* row = W + (g * NH + k) * NH + 8 * m4;
            o.x = pkf_(row[0], row[1]); o.y = pkf_(row[2], row[3]);
            o.z = pkf_(row[4], row[5]); o.w = pkf_(row[6], row[7]);
        } else {
            int q = p - NW4;
            int v = q % NV, r = q / NV;
            int m4 = r % 5;
            int dd = r / 5;
            const float* W = dd ? W_l2 : W_l1;
            const float* row = W + v * NH + 8 * m4;
            o.x = pkf_(row[0], row[1]); o.y = pkf_(row[2], row[3]);
            o.z = pkf_(row[4], row[5]); o.w = pkf_(row[6], row[7]);
        }
        ws[p] = o;
    }
}

// Blocks: 128 thr = 2 waves = 2 directions. Per wave: lanes 0-39 = LSTM units.
// HYBRID weight home: i,f gates (40 u32) in registers (live set ~72 fits under
// the allocator's observed ~88 cap -> no spill); g,o gates in LDS (10
// ds_read_b128/step, opaque-offset to defeat LICM). Lanes 40-59 = logit riders
// on the i-gate dot chain. Triple-buffered f16 u-ring, 1 barrier / 32 steps.
extern "C" __global__ void
__attribute__((amdgpu_waves_per_eu(1, 2), amdgpu_flat_work_group_size(NTHR, NTHR)))
bilstm_kernel(const int* __restrict__ tokens,
              const float* __restrict__ embed,
              const float* __restrict__ W_ih1,
              const float* __restrict__ b_ih1, const float* __restrict__ b_hh1,
              const float* __restrict__ W_ih2,
              const float* __restrict__ b_ih2, const float* __restrict__ b_hh2,
              const float* __restrict__ b_l1,  const float* __restrict__ b_l2,
              const uint4* __restrict__ wpk,
              float* __restrict__ out)
{
    __shared__ __align__(16) u32x2 xtab[2][NV][NH];          // f16-pair x-pre
    __shared__ __align__(16) u32x4 WgoS[2][2][5][NH];        // g,o gate weights
    __shared__ __align__(16) unsigned short uring[3][2][SS][NV]; // f16 u-ring
    __shared__ __align__(16) float embS[NV * NE];
    __shared__ float biasS[NV];
    __shared__ int   tokS[2][SPC];

    const int tid  = threadIdx.x;
    const int wave = tid >> 6;          // == direction
    const int lane = tid & 63;
    const int dir  = wave;
    const int a    = blockIdx.x * CHUNK;

    // ---- stage embed + tokens + bias + g/o weights ----
    for (int p = tid; p < NV * NE; p += NTHR) embS[p] = embed[p];
    for (int p = tid; p < SPC; p += NTHR) {
        int t = a - WARM + p;
        if (t >= 0) {
            tokS[0][p] = tokens[t];
            tokS[1][p] = tokens[T_LEN - 1 - t];
        }
    }
    if (tid < NV) biasS[tid] = b_l1[tid] + b_l2[tid];
    {   // WgoS[dir][gg][m4][k] <- wpk[((dir*4+2+gg)*5+m4)*40+k]
        uint4* dst = (uint4*)WgoS;
        for (int p = tid; p < 800; p += NTHR) {
            int k = p % NH, r = p / NH;
            int m4 = r % 5;  r /= 5;
            int gg = r % 2;
            int dd = r / 2;
            dst[p] = wpk[((dd * 4 + 2 + gg) * 5 + m4) * NH + k];
        }
    }
    __syncthreads();

    // ---- build x-pre table (f16 pairs): xtab[d][v][k] = {(xi,xf),(xg,xo)} ----
    for (int p = tid; p < 2 * NV * NH; p += NTHR) {
        int k = p % NH, q = p / NH;
        int v = q % NV, dd = q / NV;
        const float* Wih = dd ? W_ih2 : W_ih1;
        const float* bi  = dd ? b_ih2 : b_ih1;
        const float* bh  = dd ? b_hh2 : b_hh1;
        float x[4];
        #pragma unroll
        for (int g = 0; g < 4; ++g) {
            int j = g * NH + k;
            float acc = bi[j] + bh[j];
            #pragma unroll
            for (int e = 0; e < NE; ++e) acc += embS[v * NE + e] * Wih[j * NE + e];
            x[g] = acc;
        }
        u32x2 pk; pk.x = pkf_(x[0], x[1]); pk.y = pkf_(x[2], x[3]);
        xtab[dd][v][k] = pk;
    }

    // ---- per-lane register weights: i,f gates only (40 u32, opaque loads) ----
    const bool isUnit  = (lane < NH);
    const bool isLogit = (lane >= NH) && (lane < NH + NV);
    const int  kli     = isUnit ? lane : NH - 1;    // clamped LDS lane index

    D20(w); D20(wf);
    if (isUnit) {
        const uint4* b0 = wpk + ((dir * 4 + 0) * 5) * NH + lane;
        const uint4* b1 = wpk + ((dir * 4 + 1) * 5) * NH + lane;
        uint4 c0, c1, c2, c3, c4;
        c0=gload16_(b0); c1=gload16_(b0+NH); c2=gload16_(b0+2*NH); c3=gload16_(b0+3*NH); c4=gload16_(b0+4*NH);
        A20(w,  c0, c1, c2, c3, c4);
        c0=gload16_(b1); c1=gload16_(b1+NH); c2=gload16_(b1+2*NH); c3=gload16_(b1+3*NH); c4=gload16_(b1+4*NH);
        A20(wf, c0, c1, c2, c3, c4);
    } else {
        int vv = isLogit ? (lane - NH) : 0;
        const uint4* bl = wpk + NW4 + (dir * 5) * NV + vv;
        uint4 c0, c1, c2, c3, c4;
        c0=gload16_(bl); c1=gload16_(bl+NV); c2=gload16_(bl+2*NV); c3=gload16_(bl+3*NV); c4=gload16_(bl+4*NV);
        A20(w, c0, c1, c2, c3, c4);
        A20(wf, c0, c1, c2, c3, c4);   // dummy (af unused on rider lanes)
    }
    __syncthreads();   // xtab + tokS + WgoS ready

    // ---- init + first x prefetch ----
    const int cell_ss0 = (a < WARM) ? WUSS : 0;   // block 0 starts exactly at s=WARM
    int   hb = 0;                                  // f16 bits of own h (lanes 0-39)
    float c  = 0.f;
    u32x2 xv;
    {
        int tk = tokS[dir][cell_ss0 * SS];
        xv = xtab[dir][tk][kli];
    }

    // ---- main loop (super-step NSS = 1 extra iteration to finish last batch) ----
    #pragma unroll 1
    for (int ss = cell_ss0; ss <= NSS; ++ss) {
        const int sbase = ss * SS;
        const int nsl   = (ss < NSS) ? SS : 1;
        #pragma unroll 1
        for (int sl = 0; sl < nsl; ++sl) {
            const int s = sbase + sl;
            // opaque base offset: keeps the loop-invariant WgoS reads in-loop
            unsigned wofs = 0;
            asm volatile("" : "+v"(wofs));
            const u32x4* wgo = &WgoS[dir][0][0][kli] + wofs;
            // pack h pairs via DPP quad_perm [1,0,3,2] (xor lane bit 0)
            unsigned nb = (unsigned)__builtin_amdgcn_mov_dpp((int)hb, 0xB1, 0xF, 0xF, true);
            unsigned hpair = ((unsigned)hb & 0xffffu) | (nb << 16);
            float ai = 0.f, af = 0.f, ag = 0.f, ao = 0.f;
            if (isUnit) {
                ai = lo16f_(xv.x); af = hi16f_(xv.x);
                ag = lo16f_(xv.y); ao = hi16f_(xv.y);
            }
            ACHUNK(0,  0,  1,  2,  3);
            ACHUNK(1,  4,  5,  6,  7);
            ACHUNK(2,  8,  9, 10, 11);
            ACHUNK(3, 12, 13, 14, 15);
            ACHUNK(4, 16, 17, 18, 19);
            const float uval = ai;                  // logit lanes: u = h_{s-1}·W_l
            if (isLogit && s >= 1) {                // belongs to output step s-1
                int us = s - 1;
                uring[(us >> 5) % 3][dir][us & 31][lane - NH] =
                    __half_as_ushort(__float2half(uval));
            }
            int sn = (s + 1 < SPC) ? s + 1 : SPC - 1;
            int tk = tokS[dir][sn];
            xv = xtab[dir][tk][kli];                // prefetch next x
            float I = sig_(ai), F = sig_(af), G = tanh_(ag), O = sig_(ao);
            c = fmaf(F, c, I * G);
            float hh = O * tanh_(c);
            hb = (int)__half_as_ushort(__float2half(hh));
        }
        __syncthreads();
        if (wave == 0 && ss > WUSS) {               // store finished batch B = ss-1
            const int B   = ss - 1;
            const int buf = B % 3;
            const size_t rbase = (size_t)(a + B * SS - WARM) * NV;
            #pragma unroll
            for (int i = 0; i < (SS * NV) / 64; ++i) {   // 10
                int e = i * 64 + lane;
                int row = e / NV, v = e - row * NV;
                float sum = __half2float(__ushort_as_half(uring[buf][0][row][v]))
                          + __half2float(__ushort_as_half(uring[buf][1][row][v]))
                          + biasS[v];
                out[rbase + e] = sum;
            }
        }
    }
}

extern "C" void kernel_launch(void* const* d_in, const int* in_sizes, int n_in,
                              void* d_out, int out_size, void* d_ws, size_t ws_size,
                              hipStream_t stream)
{
    const int*   tokens = (const int*)  d_in[0];
    const float* embed  = (const float*)d_in[1];
    const float* W_ih1  = (const float*)d_in[2];
    const float* W_hh1  = (const float*)d_in[3];
    const float* b_ih1  = (const float*)d_in[4];
    const float* b_hh1  = (const float*)d_in[5];
    const float* W_ih2  = (const float*)d_in[6];
    const float* W_hh2  = (const float*)d_in[7];
    const float* b_ih2  = (const float*)d_in[8];
    const float* b_hh2  = (const float*)d_in[9];
    const float* W_l1   = (const float*)d_in[10];
    const float* b_l1   = (const float*)d_in[11];
    const float* W_l2   = (const float*)d_in[12];
    const float* b_l2   = (const float*)d_in[13];
    float* outp = (float*)d_out;
    uint4* wpk  = (uint4*)d_ws;

    hipLaunchKernelGGL(prep_kernel, dim3(8), dim3(256), 0, stream,
                       W_hh1, W_hh2, W_l1, W_l2, wpk);
    hipLaunchKernelGGL(bilstm_kernel, dim3(NBLK), dim3(NTHR), 0, stream,
                       tokens, embed, W_ih1, b_ih1, b_hh1,
                       W_ih2, b_ih2, b_hh2, b_l1, b_l2, wpk, outp);
}